// Round 4
// baseline (13274.921 us; speedup 1.0000x reference)
//
#include <hip/hip_runtime.h>

// ---------------------------------------------------------------------------
// 2-layer LSTM LM forward, MI355X persistent-kernel design, round 4.
//
//   round r (1..4097): layer0 computes step r, layer1 computes step r-1.
//   h travels as TAG-EMBEDDED u64 words ((round<<32)|bf16x2) polled with
//   16B coherent loads (sc0 sc1), published with 16B coherent stores.
//   Recurrent weights live in VGPRs (64/thread); LDS only stages v/gates.
// ---------------------------------------------------------------------------

#define T_SEQ 4096
#define HID   1024
#define EMBD  512
#define VOCAB 50257
#define NBLK  256
#define TPB   512
#define UB    4      // hidden units per block per layer
#define NSEG0 48     // (EMBD+HID)/32 k-segments, layer 0
#define NSEG1 64     // (HID+HID)/32  k-segments, layer 1

// workspace layout (32-bit word offsets)
#define WS_H0T 0       // u64[2][512]: (tag<<32)|bf16pair
#define WS_H1T 2048    // u64[2][512]
#define WS_H1F 4096    // float[1024] final h1
#define WS_LOG 5120    // float[50257] logits
#define WS_LSE 55377   // float[1]

// LDS layout (bytes)
#define OFF_W0 0                   // short8[NSEG0*64]  = 49152 (staging only)
#define OFF_W1 49152               // short8[NSEG1*64]  = 65536 (staging only)
#define OFF_V0 114688              // bf16[1536]  (x_t || h0_{r-1})
#define OFF_V1 117760              // bf16[2048]  (h0_{r-1} || h1_{r-2})
#define OFF_GP 121856              // float[7][16] gate partials
#define OFF_B0 122304              // float[16]
#define OFF_B1 122368              // float[16]
#define SMEM_BYTES 122432

typedef __attribute__((ext_vector_type(8))) short short8;
typedef __attribute__((ext_vector_type(4))) float f32x4;
typedef __attribute__((ext_vector_type(4))) unsigned int u32x4;
typedef unsigned long long u64;

__device__ __forceinline__ unsigned short f2bf(float f) {
  unsigned int u = __float_as_uint(f);
  u += 0x7FFFu + ((u >> 16) & 1u);          // round-to-nearest-even
  return (unsigned short)(u >> 16);
}
__device__ __forceinline__ unsigned int pack2bf(float a, float b) {
  return (unsigned int)f2bf(a) | ((unsigned int)f2bf(b) << 16);
}
__device__ __forceinline__ float sigmoidf_(float x) {
  return 1.f / (1.f + __expf(-x));
}
__device__ __forceinline__ float tanhf_(float x) {
  return 1.f - 2.f / (__expf(2.f * x) + 1.f);
}

// 16B coherent (device-scope) load/store: bypass L1/L2 to the coherence
// point, same semantics as agent-scope relaxed atomics but 2 words/op.
// Tag checks make any per-8B staleness a retry, never a wrong value.
__device__ __forceinline__ u32x4 load16_cohere(const void* p) {
  u32x4 r;
  asm volatile("global_load_dwordx4 %0, %1, off sc0 sc1\n\ts_waitcnt vmcnt(0)"
               : "=v"(r) : "v"((u64)p) : "memory");
  return r;
}
__device__ __forceinline__ void store16_cohere(void* p, u32x4 v) {
  asm volatile("global_store_dwordx4 %0, %1, off sc0 sc1"
               :: "v"((u64)p), "v"(v) : "memory");
}

// 16 MFMA k-segments, weights in registers. A = v replicated across the 16
// rows (broadcast LDS read; any lane->k map cancels between A and B since
// both were packed with the same map). D: col=lane&15 = gate-row.
__device__ __forceinline__ void mmv(const short8* vf, const short8 (&wr)[16],
                                    int s0, int grp, float* gout, int lane) {
  f32x4 a0 = {0.f, 0.f, 0.f, 0.f};
  f32x4 a1 = a0, a2 = a0, a3 = a0;
#pragma unroll
  for (int i = 0; i < 16; ++i) {
    short8 av = vf[(s0 + i) * 4 + grp];
    if ((i & 3) == 0)      a0 = __builtin_amdgcn_mfma_f32_16x16x32_bf16(av, wr[i], a0, 0, 0, 0);
    else if ((i & 3) == 1) a1 = __builtin_amdgcn_mfma_f32_16x16x32_bf16(av, wr[i], a1, 0, 0, 0);
    else if ((i & 3) == 2) a2 = __builtin_amdgcn_mfma_f32_16x16x32_bf16(av, wr[i], a2, 0, 0, 0);
    else                   a3 = __builtin_amdgcn_mfma_f32_16x16x32_bf16(av, wr[i], a3, 0, 0, 0);
  }
  f32x4 s = (a0 + a1) + (a2 + a3);
  if (lane < 16) gout[lane] = s[0];
}

// ---------------------------------------------------------------------------
__global__ __launch_bounds__(TPB, 1) void reset_kernel(
    const float* __restrict__ h0in, unsigned int* __restrict__ ws) {
  const int tid = threadIdx.x;
  u64* H0T = reinterpret_cast<u64*>(ws + WS_H0T);
  u64* H1T = reinterpret_cast<u64*>(ws + WS_H1T);
  // slot 0 <- initial hidden states with tag 0; slot 1 <- INVALID tag.
  // (slot-1 invalidation kills the cross-replay stale-tag race at rounds
  //  4096/4097: leftover tags 4095/4096 from a prior replay would collide
  //  with the expected tags of the final rounds.)
  H0T[tid] = (u64)pack2bf(h0in[2 * tid], h0in[2 * tid + 1]);
  H1T[tid] = (u64)pack2bf(h0in[HID + 2 * tid], h0in[HID + 2 * tid + 1]);
  H0T[512 + tid] = 0xFFFFFFFF00000000ULL;
  H1T[512 + tid] = 0xFFFFFFFF00000000ULL;
}

// ---------------------------------------------------------------------------
__global__ __launch_bounds__(TPB, 1) void scan_kernel(
    const int* __restrict__ tok,
    const float* __restrict__ h0in, const float* __restrict__ c0in,
    const float* __restrict__ emb,
    const float* __restrict__ wih0, const float* __restrict__ whh0,
    const float* __restrict__ bih0, const float* __restrict__ bhh0,
    const float* __restrict__ wih1, const float* __restrict__ whh1,
    const float* __restrict__ bih1, const float* __restrict__ bhh1,
    float* __restrict__ dout, unsigned int* __restrict__ ws) {
  extern __shared__ char smem[];
  short8* W0f = reinterpret_cast<short8*>(smem + OFF_W0);
  short8* W1f = reinterpret_cast<short8*>(smem + OFF_W1);
  unsigned int* v0w = reinterpret_cast<unsigned int*>(smem + OFF_V0);
  unsigned int* v1w = reinterpret_cast<unsigned int*>(smem + OFF_V1);
  const short8* v0f = reinterpret_cast<const short8*>(smem + OFF_V0);
  const short8* v1f = reinterpret_cast<const short8*>(smem + OFF_V1);
  float* gp  = reinterpret_cast<float*>(smem + OFF_GP);
  float* bs0 = reinterpret_cast<float*>(smem + OFF_B0);
  float* bs1 = reinterpret_cast<float*>(smem + OFF_B1);

  const int tid = threadIdx.x;
  const int bid = blockIdx.x;
  const int lane = tid & 63;
  const int w = tid >> 6;
  const int grp = lane >> 4;

  // ---- stage weights into LDS as pre-swizzled B-fragments (bf16) ----
  for (int slot = tid; slot < NSEG0 * 64; slot += TPB) {
    const int seg = slot >> 6, l = slot & 63;
    const int col = l & 15, g = l >> 4;
    const int grow = (col >> 2) * HID + bid * UB + (col & 3);
    const int k0 = seg * 32 + g * 8;
    const float* src = (k0 < EMBD) ? (wih0 + (size_t)grow * EMBD + k0)
                                   : (whh0 + (size_t)grow * HID + (k0 - EMBD));
    const float4* s4 = reinterpret_cast<const float4*>(src);
    float4 f0 = s4[0], f1 = s4[1];
    short8 pk;
    pk[0] = (short)f2bf(f0.x); pk[1] = (short)f2bf(f0.y);
    pk[2] = (short)f2bf(f0.z); pk[3] = (short)f2bf(f0.w);
    pk[4] = (short)f2bf(f1.x); pk[5] = (short)f2bf(f1.y);
    pk[6] = (short)f2bf(f1.z); pk[7] = (short)f2bf(f1.w);
    W0f[slot] = pk;
  }
  for (int slot = tid; slot < NSEG1 * 64; slot += TPB) {
    const int seg = slot >> 6, l = slot & 63;
    const int col = l & 15, g = l >> 4;
    const int grow = (col >> 2) * HID + bid * UB + (col & 3);
    const int k0 = seg * 32 + g * 8;
    const float* src = (k0 < HID) ? (wih1 + (size_t)grow * HID + k0)
                                  : (whh1 + (size_t)grow * HID + (k0 - HID));
    const float4* s4 = reinterpret_cast<const float4*>(src);
    float4 f0 = s4[0], f1 = s4[1];
    short8 pk;
    pk[0] = (short)f2bf(f0.x); pk[1] = (short)f2bf(f0.y);
    pk[2] = (short)f2bf(f0.z); pk[3] = (short)f2bf(f0.w);
    pk[4] = (short)f2bf(f1.x); pk[5] = (short)f2bf(f1.y);
    pk[6] = (short)f2bf(f1.z); pk[7] = (short)f2bf(f1.w);
    W1f[slot] = pk;
  }
  if (tid < 16) {
    const int grow = (tid >> 2) * HID + bid * UB + (tid & 3);
    bs0[tid] = bih0[grow] + bhh0[grow];
  } else if (tid < 32) {
    const int c = tid - 16;
    const int grow = (c >> 2) * HID + bid * UB + (c & 3);
    bs1[c] = bih1[grow] + bhh1[grow];
  }
  __syncthreads();

  // ---- pull this wave's 16 weight fragments into registers ----
  short8 wr[16];
  {
    const short8* wf = (w < 3) ? W0f : W1f;
    const int s0 = (w < 3) ? w * 16 : (w - 3) * 16;
    if (w < 7) {
#pragma unroll
      for (int i = 0; i < 16; ++i) wr[i] = wf[(s0 + i) * 64 + lane];
    }
  }

  // cell state: wave0 lanes 0-3 hold layer0 c; wave3 lanes 0-3 hold layer1 c
  float cst = 0.f;
  if (w == 0 && lane < UB) cst = c0in[bid * UB + lane];
  if (w == 3 && lane < UB) cst = c0in[HID + bid * UB + lane];

  // prefetch x for round 1
  float xa = 0.f, xb = 0.f;
  if (tid < 256) {
    const float* xp = emb + (size_t)tok[0] * EMBD + tid * 2;
    xa = xp[0]; xb = xp[1];
  }

  u64* H0T = reinterpret_cast<u64*>(ws + WS_H0T);
  u64* H1T = reinterpret_cast<u64*>(ws + WS_H1T);

  for (int r = 1; r <= T_SEQ + 1; ++r) {
    // ---- x_r to LDS; issue x_{r+1} prefetch (drains during poll) ----
    if (tid < 256) {
      v0w[tid] = pack2bf(xa, xb);
      const int ridx = (r < T_SEQ) ? r : (T_SEQ - 1);
      const float* xp = emb + (size_t)tok[ridx] * EMBD + tid * 2;
      xa = xp[0]; xb = xp[1];
    }

    // ---- poll tagged ring words, 16B (= 2 words) per thread ----
    if (tid < 256) {
      const unsigned int tg0 = (unsigned int)(r - 1);
      const u64* src = &H0T[((r - 1) & 1) * 512 + 2 * tid];
      u32x4 q;
      do { q = load16_cohere(src); } while (q.y != tg0 || q.w != tg0);
      const u64 pair = (u64)q.x | ((u64)q.z << 32);
      *reinterpret_cast<u64*>(&v0w[256 + 2 * tid]) = pair;  // v0 hi half
      *reinterpret_cast<u64*>(&v1w[2 * tid]) = pair;        // v1 lo half
    } else if (r >= 2) {
      const int t2 = tid - 256;
      const unsigned int tg1 = (unsigned int)(r - 2);
      const u64* src = &H1T[(r & 1) * 512 + 2 * t2];        // (r-2)&1 == r&1
      u32x4 q;
      do { q = load16_cohere(src); } while (q.y != tg1 || q.w != tg1);
      *reinterpret_cast<u64*>(&v1w[512 + 2 * t2]) = (u64)q.x | ((u64)q.z << 32);
    }
    __syncthreads();

    // ---- mm from register weights: waves 0-2 layer0, waves 3-6 layer1 ----
    if (w < 3) {
      if (r <= T_SEQ) mmv(v0f, wr, w * 16, grp, gp + w * 16, lane);
    } else if (w < 7) {
      if (r >= 2) mmv(v1f, wr, (w - 3) * 16, grp, gp + w * 16, lane);
    }
    __syncthreads();

    // ---- gates + tagged 16B publish (wave0: layer0; wave3: layer1) ----
    if (w == 0 && r <= T_SEQ) {
      float hv = 0.f;
      if (lane < UB) {
        const int u = lane;
        float gi = bs0[u], gf = bs0[4 + u], gg = bs0[8 + u], go = bs0[12 + u];
#pragma unroll
        for (int p = 0; p < 3; ++p) {
          gi += gp[p * 16 + u];      gf += gp[p * 16 + 4 + u];
          gg += gp[p * 16 + 8 + u];  go += gp[p * 16 + 12 + u];
        }
        const float c = sigmoidf_(gf) * cst + sigmoidf_(gi) * tanhf_(gg);
        cst = c;
        hv = sigmoidf_(go) * tanhf_(c);
        if (r == T_SEQ) {
          dout[VOCAB + bid * UB + u] = hv;              // h_n layer0
          dout[VOCAB + 2 * HID + bid * UB + u] = cst;   // c_n layer0
        }
      }
      const float h0v = __shfl(hv, 0), h1v = __shfl(hv, 1);
      const float h2v = __shfl(hv, 2), h3v = __shfl(hv, 3);
      if (lane == 0) {
        u32x4 word;
        word.x = pack2bf(h0v, h1v); word.y = (unsigned int)r;
        word.z = pack2bf(h2v, h3v); word.w = (unsigned int)r;
        store16_cohere(&H0T[(r & 1) * 512 + bid * 2], word);
      }
    }
    if (w == 3 && r >= 2) {
      float hv = 0.f;
      if (lane < UB) {
        const int u = lane;
        float gi = bs1[u], gf = bs1[4 + u], gg = bs1[8 + u], go = bs1[12 + u];
#pragma unroll
        for (int p = 3; p < 7; ++p) {
          gi += gp[p * 16 + u];      gf += gp[p * 16 + 4 + u];
          gg += gp[p * 16 + 8 + u];  go += gp[p * 16 + 12 + u];
        }
        const float c = sigmoidf_(gf) * cst + sigmoidf_(gi) * tanhf_(gg);
        cst = c;
        hv = sigmoidf_(go) * tanhf_(c);
        if (r - 1 == T_SEQ) {
          float* h1f = reinterpret_cast<float*>(ws + WS_H1F);
          h1f[bid * UB + u] = hv;
          dout[VOCAB + HID + bid * UB + u] = hv;            // h_n layer1
          dout[VOCAB + 3 * HID + bid * UB + u] = cst;       // c_n layer1
        }
      }
      const float h0v = __shfl(hv, 0), h1v = __shfl(hv, 1);
      const float h2v = __shfl(hv, 2), h3v = __shfl(hv, 3);
      if (lane == 0) {
        u32x4 word;
        word.x = pack2bf(h0v, h1v); word.y = (unsigned int)(r - 1);
        word.z = pack2bf(h2v, h3v); word.w = (unsigned int)(r - 1);
        store16_cohere(&H1T[((r - 1) & 1) * 512 + bid * 2], word);
      }
    }
    // no trailing barrier: v-writes for round r+1 happen only after polls
    // see all blocks' round-r publishes, which follow this block's sync(2).
  }
}

// ---------------------------------------------------------------------------
__global__ __launch_bounds__(256) void logits_kernel(
    const float* __restrict__ wout, const float* __restrict__ bout,
    unsigned int* __restrict__ ws) {
  const float* h1f = reinterpret_cast<const float*>(ws + WS_H1F);
  float* lg = reinterpret_cast<float*>(ws + WS_LOG);
  const int lane = threadIdx.x & 63;
  const int wv = threadIdx.x >> 6;
  const int gw = blockIdx.x * 4 + wv;    // 1024 waves total
  const float4* h4 = reinterpret_cast<const float4*>(h1f);
  float4 h[4];
#pragma unroll
  for (int j = 0; j < 4; ++j) h[j] = h4[j * 64 + lane];
  for (int v = gw; v < VOCAB; v += 1024) {
    const float4* wr = reinterpret_cast<const float4*>(wout + (size_t)v * HID);
    float s = 0.f;
#pragma unroll
    for (int j = 0; j < 4; ++j) {
      float4 x = wr[j * 64 + lane];
      s += x.x * h[j].x + x.y * h[j].y + x.z * h[j].z + x.w * h[j].w;
    }
#pragma unroll
    for (int m = 32; m >= 1; m >>= 1) s += __shfl_xor(s, m, 64);
    if (lane == 0) lg[v] = s + bout[v];
  }
}

__global__ __launch_bounds__(1024) void lse_kernel(unsigned int* __restrict__ ws) {
  const float* lg = reinterpret_cast<const float*>(ws + WS_LOG);
  __shared__ float wred[16];
  __shared__ float mshare;
  const int tid = threadIdx.x;
  float m = -3.4e38f;
  for (int i = tid; i < VOCAB; i += 1024) m = fmaxf(m, lg[i]);
#pragma unroll
  for (int s = 32; s >= 1; s >>= 1) m = fmaxf(m, __shfl_xor(m, s, 64));
  if ((tid & 63) == 0) wred[tid >> 6] = m;
  __syncthreads();
  if (tid == 0) {
    float mm = wred[0];
    for (int i = 1; i < 16; ++i) mm = fmaxf(mm, wred[i]);
    mshare = mm;
  }
  __syncthreads();
  const float M = mshare;
  float a = 0.f;
  for (int i = tid; i < VOCAB; i += 1024) a += __expf(lg[i] - M);
#pragma unroll
  for (int s = 32; s >= 1; s >>= 1) a += __shfl_xor(a, s, 64);
  __syncthreads();
  if ((tid & 63) == 0) wred[tid >> 6] = a;
  __syncthreads();
  if (tid == 0) {
    float ss = 0.f;
    for (int i = 0; i < 16; ++i) ss += wred[i];
    reinterpret_cast<float*>(ws + WS_LSE)[0] = M + logf(ss);
  }
}

__global__ __launch_bounds__(256) void out_kernel(
    const unsigned int* __restrict__ ws, float* __restrict__ dout) {
  const float lse = reinterpret_cast<const float*>(ws + WS_LSE)[0];
  const float* lg = reinterpret_cast<const float*>(ws + WS_LOG);
  const int i = blockIdx.x * 256 + threadIdx.x;
  if (i < VOCAB) dout[i] = lg[i] - lse;
}

// ---------------------------------------------------------------------------
extern "C" void kernel_launch(void* const* d_in, const int* in_sizes, int n_in,
                              void* d_out, int out_size, void* d_ws, size_t ws_size,
                              hipStream_t stream) {
  const int*   tok  = (const int*)d_in[0];
  const float* h0in = (const float*)d_in[1];
  const float* c0in = (const float*)d_in[2];
  const float* emb  = (const float*)d_in[3];
  const float* wih0 = (const float*)d_in[4];
  const float* whh0 = (const float*)d_in[5];
  const float* bih0 = (const float*)d_in[6];
  const float* bhh0 = (const float*)d_in[7];
  const float* wih1 = (const float*)d_in[8];
  const float* whh1 = (const float*)d_in[9];
  const float* bih1 = (const float*)d_in[10];
  const float* bhh1 = (const float*)d_in[11];
  const float* wout = (const float*)d_in[12];
  const float* bout = (const float*)d_in[13];
  float* out = (float*)d_out;
  unsigned int* ws = (unsigned int*)d_ws;

  (void)in_sizes; (void)n_in; (void)out_size; (void)ws_size;

  (void)hipFuncSetAttribute((const void*)scan_kernel,
                            hipFuncAttributeMaxDynamicSharedMemorySize, SMEM_BYTES);

  reset_kernel<<<1, TPB, 0, stream>>>(h0in, ws);
  scan_kernel<<<NBLK, TPB, SMEM_BYTES, stream>>>(
      tok, h0in, c0in, emb, wih0, whh0, bih0, bhh0,
      wih1, whh1, bih1, bhh1, out, ws);
  logits_kernel<<<256, 256, 0, stream>>>(wout, bout, ws);
  lse_kernel<<<1, 1024, 0, stream>>>(ws);
  out_kernel<<<(VOCAB + 255) / 256, 256, 0, stream>>>(ws, out);
}